// Round 8
// baseline (277.740 us; speedup 1.0000x reference)
//
#include <hip/hip_runtime.h>
#include <math.h>

#define N_NODES 100000
#define N_EDGES 3200000
#define F_IN    37
#define H_DIM   16
#define C_DIM   2

#define BUCKET_BITS 7
#define BUCKET_SZ   128
#define NBUCK       782          // ceil(100000/128)
#define CAP         4736         // bucket capacity: mean 4092 + 10 sigma
#define CHUNK       8192
#define NCHUNK      391          // ceil(3.2M/8192)
#define EPT         8
#define EPT_S       5            // ceil(CAP/1024)

__device__ __forceinline__ unsigned bf16rne(float f) {
    unsigned u = __float_as_uint(f);
    return (u + 0x7FFFu + ((u >> 16) & 1u)) >> 16;
}
__device__ __forceinline__ int2 ldnt_i2(const int2* p) {
    long long v = __builtin_nontemporal_load((const long long*)p);
    return *(int2*)&v;
}

// ---------- init bucket cursors ----------
__global__ void k_init(int* __restrict__ gcur) {
    int i = blockIdx.x * blockDim.x + threadIdx.x;
    if (i < NBUCK) gcur[i] = i * CAP;
}

// ---------- partition edges into destination buckets ----------
// packed: (row | col_local<<17, w)
__global__ __launch_bounds__(1024) void k_part(
    const int* __restrict__ row, const int* __restrict__ col,
    const float* __restrict__ w, int* __restrict__ gcur, int2* __restrict__ ebuf)
{
    __shared__ int cnt[NBUCK];
    __shared__ int gbase[NBUCK];
    int t = threadIdx.x;
    int e0 = blockIdx.x * CHUNK;
    int bk[EPT], rc[EPT], lofs[EPT];
    float wv[EPT];

    if (t < NBUCK) cnt[t] = 0;
    __syncthreads();
#pragma unroll
    for (int k = 0; k < EPT; k++) {
        int e = e0 + k * 1024 + t;
        if (e < N_EDGES) {
            int r = __builtin_nontemporal_load(&row[e]);
            int c = __builtin_nontemporal_load(&col[e]);
            wv[k] = __builtin_nontemporal_load(&w[e]);
            bk[k] = c >> BUCKET_BITS;
            rc[k] = r | ((c & (BUCKET_SZ - 1)) << 17);
            lofs[k] = atomicAdd(&cnt[bk[k]], 1);
        } else bk[k] = -1;
    }
    __syncthreads();
    if (t < NBUCK) gbase[t] = atomicAdd(&gcur[t], cnt[t]);
    __syncthreads();
#pragma unroll
    for (int k = 0; k < EPT; k++) {
        if (bk[k] >= 0)
            ebuf[gbase[bk[k]] + lofs[k]] = make_int2(rc[k], __float_as_int(wv[k]));
    }
}

// ---------- per-bucket counting sort (in place) -> CSR rp + dinv ----------
__global__ __launch_bounds__(1024) void k_sort(
    const int* __restrict__ gcur, int2* __restrict__ ebuf,
    int2* __restrict__ rp, float* __restrict__ dinv)
{
    __shared__ int   cnt[BUCKET_SZ];
    __shared__ int   base[BUCKET_SZ];
    __shared__ float wsum[BUCKET_SZ];
    int t = threadIdx.x, b = blockIdx.x;
    int s = b * CAP;
    int len = gcur[b] - s;
    if (t < BUCKET_SZ) { cnt[t] = 0; wsum[t] = 0.f; }
    __syncthreads();

    int2 ed[EPT_S]; int cl[EPT_S], lofs[EPT_S];
#pragma unroll
    for (int k = 0; k < EPT_S; k++) {
        int i = k * 1024 + t;
        if (i < len) {
            int2 v = ldnt_i2(&ebuf[s + i]);
            ed[k] = v;
            cl[k] = v.x >> 17;
            lofs[k] = atomicAdd(&cnt[cl[k]], 1);
            atomicAdd(&wsum[cl[k]], __int_as_float(v.y));
        } else cl[k] = -1;
    }
    __syncthreads();
    // inclusive scan of cnt[128] in LDS
    if (t < BUCKET_SZ) base[t] = cnt[t];
    __syncthreads();
    for (int off = 1; off < BUCKET_SZ; off <<= 1) {
        int v2 = 0;
        if (t < BUCKET_SZ && t >= off) v2 = base[t - off];
        __syncthreads();
        if (t < BUCKET_SZ) base[t] += v2;
        __syncthreads();
    }
    // scatter back in node-sorted order
#pragma unroll
    for (int k = 0; k < EPT_S; k++) {
        if (cl[k] >= 0) {
            int pos = base[cl[k]] - cnt[cl[k]] + lofs[k];
            ebuf[s + pos] = ed[k];
        }
    }
    int c = (b << BUCKET_BITS) + t;
    if (t < BUCKET_SZ && c < N_NODES) {
        rp[c] = make_int2(s + base[t] - cnt[t], cnt[t]);
        dinv[c] = rsqrtf(wsum[t] + 1.0f);
    }
}

// ---------- h1b = bf16(dinv * (x @ W1)), x staged via LDS ----------
__global__ __launch_bounds__(256) void k_xw1(
    const float* __restrict__ x, const float* __restrict__ W1,
    const float* __restrict__ dinv, uint4* __restrict__ h1b)
{
    __shared__ float xs[256 * F_IN];          // 37.9 KB
    __shared__ float sW[F_IN * H_DIM];
    int t = threadIdx.x;
    int nb = blockIdx.x * 256;
    for (int idx = t; idx < F_IN * H_DIM; idx += 256) sW[idx] = W1[idx];
    int g0 = nb * F_IN;
    for (int idx = t; idx < 256 * F_IN; idx += 256) {
        int gi = g0 + idx;
        if (gi < N_NODES * F_IN) xs[idx] = __builtin_nontemporal_load(&x[gi]);
    }
    __syncthreads();
    int i = nb + t;
    if (i >= N_NODES) return;
    float acc[H_DIM];
#pragma unroll
    for (int j = 0; j < H_DIM; j++) acc[j] = 0.f;
    const float* xi = &xs[t * F_IN];
    for (int k = 0; k < F_IN; k++) {
        float xv = xi[k];
#pragma unroll
        for (int j = 0; j < H_DIM; j++) acc[j] += xv * sW[k * H_DIM + j];
    }
    float di = dinv[i];
    unsigned p[8];
#pragma unroll
    for (int j = 0; j < 8; j++) {
        unsigned lo = bf16rne(di * acc[2 * j]);
        unsigned hi = bf16rne(di * acc[2 * j + 1]);
        p[j] = lo | (hi << 16);
    }
    h1b[(size_t)i * 2 + 0] = make_uint4(p[0], p[1], p[2], p[3]);
    h1b[(size_t)i * 2 + 1] = make_uint4(p[4], p[5], p[6], p[7]);
}

// ---------- layer 1: CSR register-accumulate over bf16 h1 rows,
//            4-deep pipelined, fused relu/bias + @W2 -> h2s ----------
__global__ __launch_bounds__(256) void k_agg1(
    const int2* __restrict__ rp, const int2* __restrict__ ebuf,
    const uint2* __restrict__ h1b, const float* __restrict__ dinv,
    const float* __restrict__ b1, const float* __restrict__ W2,
    float* __restrict__ h2s)
{
    __shared__ float sW2[H_DIM * C_DIM];
    __shared__ float sb1[H_DIM];
    int t = threadIdx.x;
    if (t < H_DIM * C_DIM) sW2[t] = W2[t];
    if (t >= 32 && t < 32 + H_DIM) sb1[t - 32] = b1[t - 32];
    __syncthreads();
    int id = blockIdx.x * 256 + t;
    int c = id >> 2, q = id & 3;
    if (c >= N_NODES) return;
    int2 seg = rp[c];
    int s = seg.x, n = seg.y;
    float4 acc = make_float4(0.f, 0.f, 0.f, 0.f);

#define PROC1(ev)                                                   \
    {   float a = __int_as_float((ev).y);                           \
        int r = (ev).x & 0x1FFFF;                                   \
        uint2 g = h1b[(size_t)r * 4 + q];                           \
        acc.x += a * __uint_as_float(g.x << 16);                    \
        acc.y += a * __uint_as_float(g.x & 0xFFFF0000u);            \
        acc.z += a * __uint_as_float(g.y << 16);                    \
        acc.w += a * __uint_as_float(g.y & 0xFFFF0000u); }

    int i = 0;
    if (n >= 4) {
        int2 e0 = ldnt_i2(&ebuf[s + 0]);
        int2 e1 = ldnt_i2(&ebuf[s + 1]);
        int2 e2 = ldnt_i2(&ebuf[s + 2]);
        int2 e3 = ldnt_i2(&ebuf[s + 3]);
        for (; i + 8 <= n; i += 4) {
            int2 f0 = ldnt_i2(&ebuf[s + i + 4]);
            int2 f1 = ldnt_i2(&ebuf[s + i + 5]);
            int2 f2 = ldnt_i2(&ebuf[s + i + 6]);
            int2 f3 = ldnt_i2(&ebuf[s + i + 7]);
            PROC1(e0); PROC1(e1); PROC1(e2); PROC1(e3);
            e0 = f0; e1 = f1; e2 = f2; e3 = f3;
        }
        PROC1(e0); PROC1(e1); PROC1(e2); PROC1(e3);
        i += 4;
    }
    for (; i < n; i++) {
        int2 ev = ldnt_i2(&ebuf[s + i]);
        PROC1(ev);
    }
#undef PROC1

    float dc = dinv[c];
    uint2 gc = h1b[(size_t)c * 4 + q];
    float hcv[4] = {__uint_as_float(gc.x << 16), __uint_as_float(gc.x & 0xFFFF0000u),
                    __uint_as_float(gc.y << 16), __uint_as_float(gc.y & 0xFFFF0000u)};
    float av[4] = {acc.x + hcv[0], acc.y + hcv[1], acc.z + hcv[2], acc.w + hcv[3]};
    int j0 = q << 2;
    float p0 = 0.f, p1 = 0.f;
#pragma unroll
    for (int j = 0; j < 4; j++) {
        float rv = fmaxf(dc * av[j] + sb1[j0 + j], 0.f);
        p0 += rv * sW2[(j0 + j) * C_DIM + 0];
        p1 += rv * sW2[(j0 + j) * C_DIM + 1];
    }
    p0 += __shfl_xor(p0, 1); p0 += __shfl_xor(p0, 2);
    p1 += __shfl_xor(p1, 1); p1 += __shfl_xor(p1, 2);
    if (q == 0) ((float2*)h2s)[c] = make_float2(dc * p0, dc * p1);
}

// ---------- layer 2: CSR register-accumulate, 4-deep pipelined,
//            + bias + log_softmax ----------
__global__ __launch_bounds__(256) void k_agg2(
    const int2* __restrict__ rp, const int2* __restrict__ ebuf,
    const float* __restrict__ h2s, const float* __restrict__ dinv,
    const float* __restrict__ b2, float* __restrict__ out)
{
    int c = blockIdx.x * 256 + threadIdx.x;
    if (c >= N_NODES) return;
    int2 seg = rp[c];
    int s = seg.x, n = seg.y;
    const float2* h22 = (const float2*)h2s;
    float a0 = 0.f, a1 = 0.f;

#define PROC2(ev)                                                   \
    {   float a = __int_as_float((ev).y);                           \
        float2 hv = h22[(ev).x & 0x1FFFF];                          \
        a0 += a * hv.x;  a1 += a * hv.y; }

    int i = 0;
    if (n >= 4) {
        int2 e0 = ldnt_i2(&ebuf[s + 0]);
        int2 e1 = ldnt_i2(&ebuf[s + 1]);
        int2 e2 = ldnt_i2(&ebuf[s + 2]);
        int2 e3 = ldnt_i2(&ebuf[s + 3]);
        for (; i + 8 <= n; i += 4) {
            int2 f0 = ldnt_i2(&ebuf[s + i + 4]);
            int2 f1 = ldnt_i2(&ebuf[s + i + 5]);
            int2 f2 = ldnt_i2(&ebuf[s + i + 6]);
            int2 f3 = ldnt_i2(&ebuf[s + i + 7]);
            PROC2(e0); PROC2(e1); PROC2(e2); PROC2(e3);
            e0 = f0; e1 = f1; e2 = f2; e3 = f3;
        }
        PROC2(e0); PROC2(e1); PROC2(e2); PROC2(e3);
        i += 4;
    }
    for (; i < n; i++) {
        int2 ev = ldnt_i2(&ebuf[s + i]);
        PROC2(ev);
    }
#undef PROC2

    float dc = dinv[c];
    float2 hc = h22[c];
    float l0 = dc * (a0 + hc.x) + b2[0];
    float l1 = dc * (a1 + hc.y) + b2[1];
    float m = fmaxf(l0, l1);
    float lse = m + logf(expf(l0 - m) + expf(l1 - m));
    ((float2*)out)[c] = make_float2(l0 - lse, l1 - lse);
}

extern "C" void kernel_launch(void* const* d_in, const int* in_sizes, int n_in,
                              void* d_out, int out_size, void* d_ws, size_t ws_size,
                              hipStream_t stream) {
    const float* x  = (const float*)d_in[0];
    const int*   ei = (const int*)d_in[1];     // [2, E]: row then col
    const float* w  = (const float*)d_in[2];
    const float* W1 = (const float*)d_in[3];
    const float* b1 = (const float*)d_in[4];
    const float* W2 = (const float*)d_in[5];
    const float* b2 = (const float*)d_in[6];
    float* out = (float*)d_out;

    const int* row = ei;
    const int* col = ei + N_EDGES;

    // workspace layout (64B-aligned offsets)
    char* ws = (char*)d_ws;
    int*   gcur = (int*)(ws + 0);                //     3,200 B
    int2*  rp   = (int2*)(ws + 3200);            //   800,000 B (start,count per node)
    float* dinv = (float*)(ws + 803200);         //   400,000 B
    uint4* h1b  = (uint4*)(ws + 1203200);        // 3,200,000 B (bf16 16/row = 32 B)
    float* h2s  = (float*)(ws + 4403200);        //   800,000 B
    int2*  ebuf = (int2*)(ws + 5203200);         //29,628,416 B (782*4736*8)
    // end: 34,831,616 B

    k_init <<<4, 256, 0, stream>>>(gcur);
    k_part <<<NCHUNK, 1024, 0, stream>>>(row, col, w, gcur, ebuf);
    k_sort <<<NBUCK, 1024, 0, stream>>>(gcur, ebuf, rp, dinv);
    k_xw1  <<<(N_NODES + 255) / 256, 256, 0, stream>>>(x, W1, dinv, h1b);
    k_agg1 <<<(4 * N_NODES + 255) / 256, 256, 0, stream>>>(rp, ebuf, (const uint2*)h1b, dinv, b1, W2, h2s);
    k_agg2 <<<(N_NODES + 255) / 256, 256, 0, stream>>>(rp, ebuf, h2s, dinv, b2, out);
}

// Round 9
// 254.468 us; speedup vs baseline: 1.0915x; 1.0915x over previous
//
#include <hip/hip_runtime.h>
#include <math.h>

#define N_NODES 100000
#define N_EDGES 3200000
#define F_IN    37
#define H_DIM   16
#define C_DIM   2

#define BUCKET_BITS 7
#define BUCKET_SZ   128
#define NBUCK       782          // ceil(100000/128)
#define CAP         4736         // bucket capacity: mean 4092 + 10 sigma
#define CHUNK       16384
#define NCHUNK      196          // ceil(3.2M/16384)
#define EPT         16
#define EPT_S       5            // ceil(CAP/1024)

__device__ __forceinline__ unsigned bf16rne(float f) {
    unsigned u = __float_as_uint(f);
    return (u + 0x7FFFu + ((u >> 16) & 1u)) >> 16;
}
__device__ __forceinline__ int2 ldnt_i2(const int2* p) {
    long long v = __builtin_nontemporal_load((const long long*)p);
    return *(int2*)&v;
}
#define BLO(u) __uint_as_float((u) << 16)
#define BHI(u) __uint_as_float((u) & 0xFFFF0000u)

// ---------- init bucket cursors ----------
__global__ void k_init(int* __restrict__ gcur) {
    int i = blockIdx.x * blockDim.x + threadIdx.x;
    if (i < NBUCK) gcur[i] = i * CAP;
}

// ---------- partition edges into destination buckets ----------
// packed: (row | col_local<<17, w)
__global__ __launch_bounds__(1024) void k_part(
    const int* __restrict__ row, const int* __restrict__ col,
    const float* __restrict__ w, int* __restrict__ gcur, int2* __restrict__ ebuf)
{
    __shared__ int cnt[NBUCK];
    __shared__ int gbase[NBUCK];
    int t = threadIdx.x;
    int e0 = blockIdx.x * CHUNK;
    int bk[EPT], rc[EPT], lofs[EPT];
    float wv[EPT];

    if (t < NBUCK) cnt[t] = 0;
    __syncthreads();
#pragma unroll
    for (int k = 0; k < EPT; k++) {
        int e = e0 + k * 1024 + t;
        if (e < N_EDGES) {
            int r = __builtin_nontemporal_load(&row[e]);
            int c = __builtin_nontemporal_load(&col[e]);
            wv[k] = __builtin_nontemporal_load(&w[e]);
            bk[k] = c >> BUCKET_BITS;
            rc[k] = r | ((c & (BUCKET_SZ - 1)) << 17);
            lofs[k] = atomicAdd(&cnt[bk[k]], 1);
        } else bk[k] = -1;
    }
    __syncthreads();
    if (t < NBUCK) gbase[t] = atomicAdd(&gcur[t], cnt[t]);
    __syncthreads();
#pragma unroll
    for (int k = 0; k < EPT; k++) {
        if (bk[k] >= 0)
            ebuf[gbase[bk[k]] + lofs[k]] = make_int2(rc[k], __float_as_int(wv[k]));
    }
}

// ---------- per-bucket counting sort via LDS stage -> coalesced write,
//            CSR rp + dinv (no float atomics) ----------
__global__ __launch_bounds__(1024) void k_sort(
    const int* __restrict__ gcur, int2* __restrict__ ebuf,
    int2* __restrict__ rp, float* __restrict__ dinv)
{
    __shared__ int  cnt[BUCKET_SZ];
    __shared__ int  base[BUCKET_SZ];
    __shared__ int2 stage[CAP];               // 37.9 KB
    int t = threadIdx.x, b = blockIdx.x;
    int s = b * CAP;
    int len = gcur[b] - s;
    if (t < BUCKET_SZ) cnt[t] = 0;
    __syncthreads();

    int2 ed[EPT_S]; int cl[EPT_S], lofs[EPT_S];
#pragma unroll
    for (int k = 0; k < EPT_S; k++) {
        int i = k * 1024 + t;
        if (i < len) {
            int2 v = ldnt_i2(&ebuf[s + i]);
            ed[k] = v;
            cl[k] = v.x >> 17;
            lofs[k] = atomicAdd(&cnt[cl[k]], 1);
        } else cl[k] = -1;
    }
    __syncthreads();
    // inclusive scan of cnt[128]
    if (t < BUCKET_SZ) base[t] = cnt[t];
    __syncthreads();
    for (int off = 1; off < BUCKET_SZ; off <<= 1) {
        int v2 = 0;
        if (t < BUCKET_SZ && t >= off) v2 = base[t - off];
        __syncthreads();
        if (t < BUCKET_SZ) base[t] += v2;
        __syncthreads();
    }
    // scatter into LDS stage in node-sorted order
#pragma unroll
    for (int k = 0; k < EPT_S; k++) {
        if (cl[k] >= 0) {
            int pos = base[cl[k]] - cnt[cl[k]] + lofs[k];
            stage[pos] = ed[k];
        }
    }
    __syncthreads();
    // coalesced write-back of sorted bucket
    for (int i = t; i < len; i += 1024)
        ebuf[s + i] = stage[i];
    // degree + CSR entry: per-node LDS segment walk (no atomics)
    if (t < BUCKET_SZ) {
        int c = (b << BUCKET_BITS) + t;
        if (c < N_NODES) {
            int st = base[t] - cnt[t], n = cnt[t];
            float sum = 1.0f;                 // self-loop
            for (int i = 0; i < n; i++) sum += __int_as_float(stage[st + i].y);
            rp[c] = make_int2(s + st, n);
            dinv[c] = rsqrtf(sum);
        }
    }
}

// ---------- h1b = bf16(dinv * (x @ W1)), x staged via LDS ----------
__global__ __launch_bounds__(256) void k_xw1(
    const float* __restrict__ x, const float* __restrict__ W1,
    const float* __restrict__ dinv, uint4* __restrict__ h1b)
{
    __shared__ float xs[256 * F_IN];          // 37.9 KB
    __shared__ float sW[F_IN * H_DIM];
    int t = threadIdx.x;
    int nb = blockIdx.x * 256;
    for (int idx = t; idx < F_IN * H_DIM; idx += 256) sW[idx] = W1[idx];
    int g0 = nb * F_IN;
    for (int idx = t; idx < 256 * F_IN; idx += 256) {
        int gi = g0 + idx;
        if (gi < N_NODES * F_IN) xs[idx] = __builtin_nontemporal_load(&x[gi]);
    }
    __syncthreads();
    int i = nb + t;
    if (i >= N_NODES) return;
    float acc[H_DIM];
#pragma unroll
    for (int j = 0; j < H_DIM; j++) acc[j] = 0.f;
    const float* xi = &xs[t * F_IN];
    for (int k = 0; k < F_IN; k++) {
        float xv = xi[k];
#pragma unroll
        for (int j = 0; j < H_DIM; j++) acc[j] += xv * sW[k * H_DIM + j];
    }
    float di = dinv[i];
    unsigned p[8];
#pragma unroll
    for (int j = 0; j < 8; j++) {
        unsigned lo = bf16rne(di * acc[2 * j]);
        unsigned hi = bf16rne(di * acc[2 * j + 1]);
        p[j] = lo | (hi << 16);
    }
    h1b[(size_t)i * 2 + 0] = make_uint4(p[0], p[1], p[2], p[3]);
    h1b[(size_t)i * 2 + 1] = make_uint4(p[4], p[5], p[6], p[7]);
}

// ---------- layer 1: 2 lanes/node, uint4 (16B) gathers — half the L2
//            requests per edge; fused relu/bias + @W2 -> h2s ----------
__global__ __launch_bounds__(256) void k_agg1(
    const int2* __restrict__ rp, const int2* __restrict__ ebuf,
    const uint4* __restrict__ h1b, const float* __restrict__ dinv,
    const float* __restrict__ b1, const float* __restrict__ W2,
    float* __restrict__ h2s)
{
    __shared__ float sW2[H_DIM * C_DIM];
    __shared__ float sb1[H_DIM];
    int t = threadIdx.x;
    if (t < H_DIM * C_DIM) sW2[t] = W2[t];
    if (t >= 32 && t < 32 + H_DIM) sb1[t - 32] = b1[t - 32];
    __syncthreads();
    int id = blockIdx.x * 256 + t;
    int c = id >> 1, q = id & 1;              // 2 lanes per node
    if (c >= N_NODES) return;
    int2 seg = rp[c];
    int s = seg.x, n = seg.y;
    float acc[8] = {0.f, 0.f, 0.f, 0.f, 0.f, 0.f, 0.f, 0.f};

#define PROC1(ev)                                                   \
    {   float a = __int_as_float((ev).y);                           \
        int r = (ev).x & 0x1FFFF;                                   \
        uint4 g = h1b[(size_t)r * 2 + q];                           \
        acc[0] += a * BLO(g.x); acc[1] += a * BHI(g.x);             \
        acc[2] += a * BLO(g.y); acc[3] += a * BHI(g.y);             \
        acc[4] += a * BLO(g.z); acc[5] += a * BHI(g.z);             \
        acc[6] += a * BLO(g.w); acc[7] += a * BHI(g.w); }

    int i = 0;
    if (n >= 4) {
        int2 e0 = ldnt_i2(&ebuf[s + 0]);
        int2 e1 = ldnt_i2(&ebuf[s + 1]);
        int2 e2 = ldnt_i2(&ebuf[s + 2]);
        int2 e3 = ldnt_i2(&ebuf[s + 3]);
        for (; i + 8 <= n; i += 4) {
            int2 f0 = ldnt_i2(&ebuf[s + i + 4]);
            int2 f1 = ldnt_i2(&ebuf[s + i + 5]);
            int2 f2 = ldnt_i2(&ebuf[s + i + 6]);
            int2 f3 = ldnt_i2(&ebuf[s + i + 7]);
            PROC1(e0); PROC1(e1); PROC1(e2); PROC1(e3);
            e0 = f0; e1 = f1; e2 = f2; e3 = f3;
        }
        PROC1(e0); PROC1(e1); PROC1(e2); PROC1(e3);
        i += 4;
    }
    for (; i < n; i++) {
        int2 ev = ldnt_i2(&ebuf[s + i]);
        PROC1(ev);
    }
#undef PROC1

    float dc = dinv[c];
    uint4 gc = h1b[(size_t)c * 2 + q];
    float hcv[8] = {BLO(gc.x), BHI(gc.x), BLO(gc.y), BHI(gc.y),
                    BLO(gc.z), BHI(gc.z), BLO(gc.w), BHI(gc.w)};
    int j0 = q << 3;
    float p0 = 0.f, p1 = 0.f;
#pragma unroll
    for (int j = 0; j < 8; j++) {
        float rv = fmaxf(dc * (acc[j] + hcv[j]) + sb1[j0 + j], 0.f);
        p0 += rv * sW2[(j0 + j) * C_DIM + 0];
        p1 += rv * sW2[(j0 + j) * C_DIM + 1];
    }
    p0 += __shfl_xor(p0, 1);
    p1 += __shfl_xor(p1, 1);
    if (q == 0) ((float2*)h2s)[c] = make_float2(dc * p0, dc * p1);
}

// ---------- layer 2: CSR register-accumulate, 4-deep pipelined,
//            + bias + log_softmax ----------
__global__ __launch_bounds__(256) void k_agg2(
    const int2* __restrict__ rp, const int2* __restrict__ ebuf,
    const float* __restrict__ h2s, const float* __restrict__ dinv,
    const float* __restrict__ b2, float* __restrict__ out)
{
    int c = blockIdx.x * 256 + threadIdx.x;
    if (c >= N_NODES) return;
    int2 seg = rp[c];
    int s = seg.x, n = seg.y;
    const float2* h22 = (const float2*)h2s;
    float a0 = 0.f, a1 = 0.f;

#define PROC2(ev)                                                   \
    {   float a = __int_as_float((ev).y);                           \
        float2 hv = h22[(ev).x & 0x1FFFF];                          \
        a0 += a * hv.x;  a1 += a * hv.y; }

    int i = 0;
    if (n >= 4) {
        int2 e0 = ldnt_i2(&ebuf[s + 0]);
        int2 e1 = ldnt_i2(&ebuf[s + 1]);
        int2 e2 = ldnt_i2(&ebuf[s + 2]);
        int2 e3 = ldnt_i2(&ebuf[s + 3]);
        for (; i + 8 <= n; i += 4) {
            int2 f0 = ldnt_i2(&ebuf[s + i + 4]);
            int2 f1 = ldnt_i2(&ebuf[s + i + 5]);
            int2 f2 = ldnt_i2(&ebuf[s + i + 6]);
            int2 f3 = ldnt_i2(&ebuf[s + i + 7]);
            PROC2(e0); PROC2(e1); PROC2(e2); PROC2(e3);
            e0 = f0; e1 = f1; e2 = f2; e3 = f3;
        }
        PROC2(e0); PROC2(e1); PROC2(e2); PROC2(e3);
        i += 4;
    }
    for (; i < n; i++) {
        int2 ev = ldnt_i2(&ebuf[s + i]);
        PROC2(ev);
    }
#undef PROC2

    float dc = dinv[c];
    float2 hc = h22[c];
    float l0 = dc * (a0 + hc.x) + b2[0];
    float l1 = dc * (a1 + hc.y) + b2[1];
    float m = fmaxf(l0, l1);
    float lse = m + logf(expf(l0 - m) + expf(l1 - m));
    ((float2*)out)[c] = make_float2(l0 - lse, l1 - lse);
}

extern "C" void kernel_launch(void* const* d_in, const int* in_sizes, int n_in,
                              void* d_out, int out_size, void* d_ws, size_t ws_size,
                              hipStream_t stream) {
    const float* x  = (const float*)d_in[0];
    const int*   ei = (const int*)d_in[1];     // [2, E]: row then col
    const float* w  = (const float*)d_in[2];
    const float* W1 = (const float*)d_in[3];
    const float* b1 = (const float*)d_in[4];
    const float* W2 = (const float*)d_in[5];
    const float* b2 = (const float*)d_in[6];
    float* out = (float*)d_out;

    const int* row = ei;
    const int* col = ei + N_EDGES;

    // workspace layout (64B-aligned offsets)
    char* ws = (char*)d_ws;
    int*   gcur = (int*)(ws + 0);                //     3,200 B
    int2*  rp   = (int2*)(ws + 3200);            //   800,000 B (start,count per node)
    float* dinv = (float*)(ws + 803200);         //   400,000 B
    uint4* h1b  = (uint4*)(ws + 1203200);        // 3,200,000 B (bf16 16/row = 32 B)
    float* h2s  = (float*)(ws + 4403200);        //   800,000 B
    int2*  ebuf = (int2*)(ws + 5203200);         //29,628,416 B (782*4736*8)
    // end: 34,831,616 B

    k_init <<<4, 256, 0, stream>>>(gcur);
    k_part <<<NCHUNK, 1024, 0, stream>>>(row, col, w, gcur, ebuf);
    k_sort <<<NBUCK, 1024, 0, stream>>>(gcur, ebuf, rp, dinv);
    k_xw1  <<<(N_NODES + 255) / 256, 256, 0, stream>>>(x, W1, dinv, h1b);
    k_agg1 <<<(2 * N_NODES + 255) / 256, 256, 0, stream>>>(rp, ebuf, h1b, dinv, b1, W2, h2s);
    k_agg2 <<<(N_NODES + 255) / 256, 256, 0, stream>>>(rp, ebuf, h2s, dinv, b2, out);
}

// Round 10
// 222.661 us; speedup vs baseline: 1.2474x; 1.1429x over previous
//
#include <hip/hip_runtime.h>
#include <math.h>

#define N_NODES 100000
#define N_EDGES 3200000
#define F_IN    37
#define H_DIM   16
#define C_DIM   2

#define BUCKET_BITS 7
#define BUCKET_SZ   128
#define NBUCK       782          // ceil(100000/128)
#define CAP         4736         // bucket capacity: mean 4096 + 10 sigma
#define CHUNK       16384
#define NCHUNK      196          // ceil(3.2M/16384)
#define EPT         16
#define EPT_S       5            // ceil(CAP/1024)

__device__ __forceinline__ unsigned bf16rne(float f) {
    unsigned u = __float_as_uint(f);
    return (u + 0x7FFFu + ((u >> 16) & 1u)) >> 16;
}
__device__ __forceinline__ int2 ldnt_i2(const int2* p) {
    long long v = __builtin_nontemporal_load((const long long*)p);
    return *(int2*)&v;
}
#define BLO(u) __uint_as_float((u) << 16)
#define BHI(u) __uint_as_float((u) & 0xFFFF0000u)
// compact edge decode: u = (w_bf16 << 17) | row
#define EW(u)  __uint_as_float(((u) >> 17) << 16)
#define ER(u)  ((u) & 0x1FFFFu)

// ---------- init bucket cursors ----------
__global__ void k_init(int* __restrict__ gcur) {
    int i = blockIdx.x * blockDim.x + threadIdx.x;
    if (i < NBUCK) gcur[i] = i * CAP;
}

// ---------- partition edges into destination buckets ----------
// packed: (row | col_local<<17, w)
__global__ __launch_bounds__(1024) void k_part(
    const int* __restrict__ row, const int* __restrict__ col,
    const float* __restrict__ w, int* __restrict__ gcur, int2* __restrict__ ebuf)
{
    __shared__ int cnt[NBUCK];
    __shared__ int gbase[NBUCK];
    int t = threadIdx.x;
    int e0 = blockIdx.x * CHUNK;
    int bk[EPT], rc[EPT], lofs[EPT];
    float wv[EPT];

    if (t < NBUCK) cnt[t] = 0;
    __syncthreads();
#pragma unroll
    for (int k = 0; k < EPT; k++) {
        int e = e0 + k * 1024 + t;
        if (e < N_EDGES) {
            int r = __builtin_nontemporal_load(&row[e]);
            int c = __builtin_nontemporal_load(&col[e]);
            wv[k] = __builtin_nontemporal_load(&w[e]);
            bk[k] = c >> BUCKET_BITS;
            rc[k] = r | ((c & (BUCKET_SZ - 1)) << 17);
            lofs[k] = atomicAdd(&cnt[bk[k]], 1);
        } else bk[k] = -1;
    }
    __syncthreads();
    if (t < NBUCK) gbase[t] = atomicAdd(&gcur[t], cnt[t]);
    __syncthreads();
#pragma unroll
    for (int k = 0; k < EPT; k++) {
        if (bk[k] >= 0)
            ebuf[gbase[bk[k]] + lofs[k]] = make_int2(rc[k], __float_as_int(wv[k]));
    }
}

// ---------- per-bucket counting sort via LDS stage -> compact 4B edges,
//            CSR rp + dinv ----------
__global__ __launch_bounds__(1024) void k_sort(
    const int* __restrict__ gcur, const int2* __restrict__ ebuf,
    unsigned* __restrict__ ebuf4, int2* __restrict__ rp, float* __restrict__ dinv)
{
    __shared__ int  cnt[BUCKET_SZ];
    __shared__ int  base[BUCKET_SZ];
    __shared__ int2 stage[CAP];               // 37.9 KB
    int t = threadIdx.x, b = blockIdx.x;
    int s = b * CAP;
    int len = gcur[b] - s;
    if (t < BUCKET_SZ) cnt[t] = 0;
    __syncthreads();

    int2 ed[EPT_S]; int cl[EPT_S], lofs[EPT_S];
#pragma unroll
    for (int k = 0; k < EPT_S; k++) {
        int i = k * 1024 + t;
        if (i < len) {
            int2 v = ldnt_i2(&ebuf[s + i]);
            ed[k] = v;
            cl[k] = v.x >> 17;
            lofs[k] = atomicAdd(&cnt[cl[k]], 1);
        } else cl[k] = -1;
    }
    __syncthreads();
    // inclusive scan of cnt[128]
    if (t < BUCKET_SZ) base[t] = cnt[t];
    __syncthreads();
    for (int off = 1; off < BUCKET_SZ; off <<= 1) {
        int v2 = 0;
        if (t < BUCKET_SZ && t >= off) v2 = base[t - off];
        __syncthreads();
        if (t < BUCKET_SZ) base[t] += v2;
        __syncthreads();
    }
    // scatter into LDS stage in node-sorted order
#pragma unroll
    for (int k = 0; k < EPT_S; k++) {
        if (cl[k] >= 0) {
            int pos = base[cl[k]] - cnt[cl[k]] + lofs[k];
            stage[pos] = ed[k];
        }
    }
    __syncthreads();
    // coalesced compact write-back: (w_bf16 << 17) | row
    for (int i = t; i < len; i += 1024) {
        int2 v = stage[i];
        unsigned wb = bf16rne(__int_as_float(v.y));       // sign bit = 0 (w >= 0)
        ebuf4[s + i] = (wb << 17) | (unsigned)(v.x & 0x1FFFF);
    }
    // degree + CSR entry: per-node LDS segment walk (exact fp32 w)
    if (t < BUCKET_SZ) {
        int c = (b << BUCKET_BITS) + t;
        if (c < N_NODES) {
            int st = base[t] - cnt[t], n = cnt[t];
            float sum = 1.0f;                 // self-loop
            for (int i = 0; i < n; i++) sum += __int_as_float(stage[st + i].y);
            rp[c] = make_int2(s + st, n);
            dinv[c] = rsqrtf(sum);
        }
    }
}

// ---------- h1b = bf16(dinv * (x @ W1)), x staged via LDS ----------
__global__ __launch_bounds__(256) void k_xw1(
    const float* __restrict__ x, const float* __restrict__ W1,
    const float* __restrict__ dinv, uint4* __restrict__ h1b)
{
    __shared__ float xs[256 * F_IN];          // 37.9 KB
    __shared__ float sW[F_IN * H_DIM];
    int t = threadIdx.x;
    int nb = blockIdx.x * 256;
    for (int idx = t; idx < F_IN * H_DIM; idx += 256) sW[idx] = W1[idx];
    int g0 = nb * F_IN;
    for (int idx = t; idx < 256 * F_IN; idx += 256) {
        int gi = g0 + idx;
        if (gi < N_NODES * F_IN) xs[idx] = __builtin_nontemporal_load(&x[gi]);
    }
    __syncthreads();
    int i = nb + t;
    if (i >= N_NODES) return;
    float acc[H_DIM];
#pragma unroll
    for (int j = 0; j < H_DIM; j++) acc[j] = 0.f;
    const float* xi = &xs[t * F_IN];
    for (int k = 0; k < F_IN; k++) {
        float xv = xi[k];
#pragma unroll
        for (int j = 0; j < H_DIM; j++) acc[j] += xv * sW[k * H_DIM + j];
    }
    float di = dinv[i];
    unsigned p[8];
#pragma unroll
    for (int j = 0; j < 8; j++) {
        unsigned lo = bf16rne(di * acc[2 * j]);
        unsigned hi = bf16rne(di * acc[2 * j + 1]);
        p[j] = lo | (hi << 16);
    }
    h1b[(size_t)i * 2 + 0] = make_uint4(p[0], p[1], p[2], p[3]);
    h1b[(size_t)i * 2 + 1] = make_uint4(p[4], p[5], p[6], p[7]);
}

// ---------- layer 1: 8 lanes/node (4 feature-quads x 2 segment-halves),
//            8B gathers, shfl-combine, fused relu/bias + @W2 -> h2s ----------
__global__ __launch_bounds__(256) void k_agg1(
    const int2* __restrict__ rp, const unsigned* __restrict__ ebuf4,
    const uint2* __restrict__ h1b, const float* __restrict__ dinv,
    const float* __restrict__ b1, const float* __restrict__ W2,
    float* __restrict__ h2s)
{
    __shared__ float sW2[H_DIM * C_DIM];
    __shared__ float sb1[H_DIM];
    int t = threadIdx.x;
    if (t < H_DIM * C_DIM) sW2[t] = W2[t];
    if (t >= 32 && t < 32 + H_DIM) sb1[t - 32] = b1[t - 32];
    __syncthreads();
    int id = blockIdx.x * 256 + t;
    int c = id >> 3;                           // 8 lanes per node
    int sub = id & 7, q = sub & 3, h = sub >> 2;
    if (c >= N_NODES) return;
    int2 seg = rp[c];
    int s = seg.x, n = seg.y;
    int m = (n - h + 1) >> 1;                  // edges for this half (stride 2)
    int p0i = s + h;
    float4 acc = make_float4(0.f, 0.f, 0.f, 0.f);

#define PROC1(u)                                                    \
    {   float a = EW(u);                                            \
        uint2 g = h1b[(size_t)ER(u) * 4 + q];                       \
        acc.x += a * BLO(g.x); acc.y += a * BHI(g.x);               \
        acc.z += a * BLO(g.y); acc.w += a * BHI(g.y); }

    int k = 0;
    if (m >= 4) {
        unsigned e0 = __builtin_nontemporal_load(&ebuf4[p0i + 0]);
        unsigned e1 = __builtin_nontemporal_load(&ebuf4[p0i + 2]);
        unsigned e2 = __builtin_nontemporal_load(&ebuf4[p0i + 4]);
        unsigned e3 = __builtin_nontemporal_load(&ebuf4[p0i + 6]);
        for (; k + 8 <= m; k += 4) {
            unsigned f0 = __builtin_nontemporal_load(&ebuf4[p0i + 2 * (k + 4)]);
            unsigned f1 = __builtin_nontemporal_load(&ebuf4[p0i + 2 * (k + 5)]);
            unsigned f2 = __builtin_nontemporal_load(&ebuf4[p0i + 2 * (k + 6)]);
            unsigned f3 = __builtin_nontemporal_load(&ebuf4[p0i + 2 * (k + 7)]);
            PROC1(e0); PROC1(e1); PROC1(e2); PROC1(e3);
            e0 = f0; e1 = f1; e2 = f2; e3 = f3;
        }
        PROC1(e0); PROC1(e1); PROC1(e2); PROC1(e3);
        k += 4;
    }
    for (; k < m; k++) {
        unsigned u = __builtin_nontemporal_load(&ebuf4[p0i + 2 * k]);
        PROC1(u);
    }
#undef PROC1

    // combine the two segment halves (lanes differ in bit2 of sub)
    acc.x += __shfl_xor(acc.x, 4);
    acc.y += __shfl_xor(acc.y, 4);
    acc.z += __shfl_xor(acc.z, 4);
    acc.w += __shfl_xor(acc.w, 4);

    float dc = dinv[c];
    uint2 gc = h1b[(size_t)c * 4 + q];
    float hcv[4] = {BLO(gc.x), BHI(gc.x), BLO(gc.y), BHI(gc.y)};
    float av[4] = {acc.x + hcv[0], acc.y + hcv[1], acc.z + hcv[2], acc.w + hcv[3]};
    int j0 = q << 2;
    float p0 = 0.f, p1 = 0.f;
#pragma unroll
    for (int j = 0; j < 4; j++) {
        float rv = fmaxf(dc * av[j] + sb1[j0 + j], 0.f);
        p0 += rv * sW2[(j0 + j) * C_DIM + 0];
        p1 += rv * sW2[(j0 + j) * C_DIM + 1];
    }
    p0 += __shfl_xor(p0, 1); p0 += __shfl_xor(p0, 2);
    p1 += __shfl_xor(p1, 1); p1 += __shfl_xor(p1, 2);
    if (sub == 0) ((float2*)h2s)[c] = make_float2(dc * p0, dc * p1);
}

// ---------- layer 2: 4 lanes/node (segment quarters), shfl reduce,
//            + bias + log_softmax ----------
__global__ __launch_bounds__(256) void k_agg2(
    const int2* __restrict__ rp, const unsigned* __restrict__ ebuf4,
    const float* __restrict__ h2s, const float* __restrict__ dinv,
    const float* __restrict__ b2, float* __restrict__ out)
{
    int id = blockIdx.x * 256 + threadIdx.x;
    int c = id >> 2, sub = id & 3;
    if (c >= N_NODES) return;
    int2 seg = rp[c];
    int s = seg.x, n = seg.y;
    const float2* h22 = (const float2*)h2s;
    int m = (n - sub + 3) >> 2;                // edges for this quarter (stride 4)
    int p0i = s + sub;
    float a0 = 0.f, a1 = 0.f;

#define PROC2(u)                                                    \
    {   float a = EW(u);                                            \
        float2 hv = h22[ER(u)];                                     \
        a0 += a * hv.x;  a1 += a * hv.y; }

    int k = 0;
    if (m >= 4) {
        unsigned e0 = __builtin_nontemporal_load(&ebuf4[p0i + 0]);
        unsigned e1 = __builtin_nontemporal_load(&ebuf4[p0i + 4]);
        unsigned e2 = __builtin_nontemporal_load(&ebuf4[p0i + 8]);
        unsigned e3 = __builtin_nontemporal_load(&ebuf4[p0i + 12]);
        for (; k + 8 <= m; k += 4) {
            unsigned f0 = __builtin_nontemporal_load(&ebuf4[p0i + 4 * (k + 4)]);
            unsigned f1 = __builtin_nontemporal_load(&ebuf4[p0i + 4 * (k + 5)]);
            unsigned f2 = __builtin_nontemporal_load(&ebuf4[p0i + 4 * (k + 6)]);
            unsigned f3 = __builtin_nontemporal_load(&ebuf4[p0i + 4 * (k + 7)]);
            PROC2(e0); PROC2(e1); PROC2(e2); PROC2(e3);
            e0 = f0; e1 = f1; e2 = f2; e3 = f3;
        }
        PROC2(e0); PROC2(e1); PROC2(e2); PROC2(e3);
        k += 4;
    }
    for (; k < m; k++) {
        unsigned u = __builtin_nontemporal_load(&ebuf4[p0i + 4 * k]);
        PROC2(u);
    }
#undef PROC2

    a0 += __shfl_xor(a0, 1); a0 += __shfl_xor(a0, 2);
    a1 += __shfl_xor(a1, 1); a1 += __shfl_xor(a1, 2);
    if (sub == 0) {
        float dc = dinv[c];
        float2 hc = h22[c];
        float l0 = dc * (a0 + hc.x) + b2[0];
        float l1 = dc * (a1 + hc.y) + b2[1];
        float mx = fmaxf(l0, l1);
        float lse = mx + logf(expf(l0 - mx) + expf(l1 - mx));
        ((float2*)out)[c] = make_float2(l0 - lse, l1 - lse);
    }
}

extern "C" void kernel_launch(void* const* d_in, const int* in_sizes, int n_in,
                              void* d_out, int out_size, void* d_ws, size_t ws_size,
                              hipStream_t stream) {
    const float* x  = (const float*)d_in[0];
    const int*   ei = (const int*)d_in[1];     // [2, E]: row then col
    const float* w  = (const float*)d_in[2];
    const float* W1 = (const float*)d_in[3];
    const float* b1 = (const float*)d_in[4];
    const float* W2 = (const float*)d_in[5];
    const float* b2 = (const float*)d_in[6];
    float* out = (float*)d_out;

    const int* row = ei;
    const int* col = ei + N_EDGES;

    // workspace layout (64B-aligned offsets)
    char* ws = (char*)d_ws;
    int*      gcur  = (int*)(ws + 0);            //     3,200 B
    int2*     rp    = (int2*)(ws + 3200);        //   800,000 B
    float*    dinv  = (float*)(ws + 803200);     //   400,000 B
    uint4*    h1b   = (uint4*)(ws + 1203200);    // 3,200,000 B (bf16 16/row)
    float*    h2s   = (float*)(ws + 4403200);    //   800,000 B
    unsigned* ebuf4 = (unsigned*)(ws + 5203200); //14,814,208 B (782*4736*4)
    int2*     ebuf  = (int2*)(ws + 20017408);    //29,628,416 B (782*4736*8)
    // end: 49,645,824 B

    k_init <<<4, 256, 0, stream>>>(gcur);
    k_part <<<NCHUNK, 1024, 0, stream>>>(row, col, w, gcur, ebuf);
    k_sort <<<NBUCK, 1024, 0, stream>>>(gcur, ebuf, ebuf4, rp, dinv);
    k_xw1  <<<(N_NODES + 255) / 256, 256, 0, stream>>>(x, W1, dinv, h1b);
    k_agg1 <<<(8 * N_NODES + 255) / 256, 256, 0, stream>>>(rp, ebuf4, (const uint2*)h1b, dinv, b1, W2, h2s);
    k_agg2 <<<(4 * N_NODES + 255) / 256, 256, 0, stream>>>(rp, ebuf4, h2s, dinv, b2, out);
}